// Round 3
// baseline (3500.633 us; speedup 1.0000x reference)
//
#include <hip/hip_runtime.h>

// Problem constants
#define EDIM 256
#define SLEN 64
#define TLEN 512
#define NT 1024
#define NWAVES 16
#define JH 128            // j-half (gate rows per role)
#define WA_ROWS 640       // 256 (Ww rows) + 384 (whh own-gate rows)
#define WAP_STRIDE 644    // LDS partial stride (bank-conflict pad)
#define GX_ROWS 384
#define GXP_STRIDE 388

__device__ __forceinline__ void st_agent(float* p, float v) {
    __hip_atomic_store(p, v, __ATOMIC_RELAXED, __HIP_MEMORY_SCOPE_AGENT);
}
__device__ __forceinline__ float ld_agent(float* p) {
    return __hip_atomic_load(p, __ATOMIC_RELAXED, __HIP_MEMORY_SCOPE_AGENT);
}

// ---- fused pack prepass ----
// z in [0,6):  whh role/gate slices   -> WA[role][k][256 + g*128 + j] = whh[g*256+role*128+j][k]
// z in [6,12): wih role/gate slices   -> wihT[role][k][g*128 + j]     = wih[g*256+role*128+j][k]
// z in [12,14): Ww for role z-12      -> WA[role][k][j]               = Ww[j][k]
__global__ __launch_bounds__(256) void pack_fused_kernel(
    const float* __restrict__ Ww, const float* __restrict__ whh,
    const float* __restrict__ wih, float* __restrict__ WA, float* __restrict__ wihT)
{
    const int z = blockIdx.z;
    const float* in; float* out; int R, C, ostride, ooff;
    if (z < 12) {
        int mat = z / 6, rem = z % 6, role = rem / 3, g = rem % 3;
        if (mat == 0) {
            in = whh + (size_t)(g * 256 + role * JH) * 256; C = 256;
            out = WA + (size_t)role * 256 * WA_ROWS; ostride = WA_ROWS; ooff = 256 + g * JH; R = JH;
        } else {
            in = wih + (size_t)(g * 256 + role * JH) * 512; C = 512;
            out = wihT + (size_t)role * 512 * GX_ROWS; ostride = GX_ROWS; ooff = g * JH; R = JH;
        }
    } else {
        int role = z - 12; in = Ww; C = 256;
        out = WA + (size_t)role * 256 * WA_ROWS; ostride = WA_ROWS; ooff = 0; R = 256;
    }
    const int r0 = blockIdx.y * 64, c0 = blockIdx.x * 64;
    if (r0 >= R || c0 >= C) return;
    __shared__ float tile[64][65];
    for (int i = threadIdx.x; i < 64 * 64; i += 256) {
        int r = i >> 6, c = i & 63;
        tile[r][c] = in[(size_t)(r0 + r) * C + (c0 + c)];
    }
    __syncthreads();
    for (int i = threadIdx.x; i < 64 * 64; i += 256) {
        int c = i >> 6, r = i & 63;
        out[(size_t)(c0 + c) * ostride + ooff + (r0 + r)] = tile[r][c];
    }
}

__global__ __launch_bounds__(NT) void gru_decoder_kernel(
    const float* __restrict__ signal,   // [B,T,E]
    const float* __restrict__ bases,    // [B,S,E]
    const int* __restrict__ mask,       // [B,T]
    const float* __restrict__ WA,       // [2][256k][640r]
    const float* __restrict__ Wb,
    const float* __restrict__ lng, const float* __restrict__ lnb,
    const float* __restrict__ wihT,     // [2][512k][384r]
    const float* __restrict__ bih, const float* __restrict__ bhh,
    const float* __restrict__ hinit,
    float* __restrict__ payload,        // [128][1024]
    unsigned int* __restrict__ flags,   // [128][64]
    float* __restrict__ out, int never)
{
    const int bid  = blockIdx.x;
    const int pair = bid >> 1;          // batch index
    const int role = bid & 1;
    const int b    = pair;
    const int joff = role * JH;
    const int tid  = threadIdx.x;
    const int lane = tid & 63;
    const int wv   = tid >> 6;

    __shared__ float h_s[EDIM], v_s[EDIM];
    __shared__ float wap[4 * WAP_STRIDE];     // A1 partials: rows 0..255 v, 256..639 gh (live to gates)
    __shared__ float ctxp[NWAVES * EDIM];
    __shared__ float mw_s[NWAVES], lw_s[NWAVES], ews_s[NWAVES];
    __shared__ float inp_s[2 * EDIM], inpn_s[2 * EDIM];
    __shared__ float gxp[8 * GXP_STRIDE];
    __shared__ float embias_s[256];           // own t-half mask bias
    __shared__ float scr2[2 * NWAVES];        // [0]=Mme [1]=Mp [2]=Lp [3]=Lme; LN partials later
    __shared__ float sWb[EDIM], sbih[768], sbhh[768], slng[512], slnb[512];
    __shared__ float pad_lds[12 * 1024];      // occupancy limiter -> 1 block/CU (co-residency)
    if (never) { pad_lds[tid] = (float)never; v_s[0] = pad_lds[(tid + 1) & 8191]; }

    const float* WAr   = WA   + (size_t)role * 256 * WA_ROWS;
    const float* wihTr = wihT + (size_t)role * 512 * GX_ROWS;
    const float* sigb  = signal + (size_t)b * TLEN * EDIM + (size_t)role * 256 * EDIM;
    const int*   maskb = mask + (size_t)b * TLEN + role * 256;

    float* mybuf = payload + (size_t)pair * 1024;
    float* myctx = mybuf + role * 320;
    float* pctx  = mybuf + (1 - role) * 320;
    float* myh   = mybuf + 640 + role * JH;
    float* ph    = mybuf + 640 + (1 - role) * JH;
    unsigned int* myflag = flags + (size_t)pair * 64 + role * 32;
    unsigned int* pflag  = flags + (size_t)pair * 64 + (1 - role) * 32;

    if (tid < 256) {
        h_s[tid] = hinit[tid];
        sWb[tid] = Wb[tid];
        embias_s[tid] = maskb[tid] ? -1e30f : 0.0f;
    }
    if (tid < 768) { sbih[tid] = bih[tid]; sbhh[tid] = bhh[tid]; }
    if (tid < 512) { slng[tid] = lng[tid]; slnb[tid] = lnb[tid]; }
    __syncthreads();

    for (int s = 0; s < SLEN; ++s) {
        // ---- A1: [v; gh_own] = WA_role @ h. 640 workers, 4-way k-split (64 k),
        //      worker owns 4 rows (float4). Threads 640..895 prefetch x into inp_s[0..255].
        if (tid < 640) {
            const int q  = tid & 3;
            const int r4 = (tid >> 2) * 4;          // 0..636
            const float* base = WAr + (size_t)(q * 64) * WA_ROWS + r4;
            const float* xk = &h_s[q * 64];
            float a0 = 0.f, a1 = 0.f, a2 = 0.f, a3 = 0.f;
#pragma unroll 8
            for (int k = 0; k < 64; ++k) {
                float4 w4 = *reinterpret_cast<const float4*>(base + (size_t)k * WA_ROWS);
                float x = xk[k];
                a0 += w4.x * x; a1 += w4.y * x; a2 += w4.z * x; a3 += w4.w * x;
            }
            float4 acc; acc.x = a0; acc.y = a1; acc.z = a2; acc.w = a3;
            *reinterpret_cast<float4*>(&wap[q * WAP_STRIDE + r4]) = acc;
        } else if (tid < 896) {
            inp_s[tid - 640] = bases[((size_t)b * SLEN + s) * EDIM + (tid - 640)];
        }
        __syncthreads();                            // (1)
        if (tid < EDIM) {
            float v = sWb[tid];
#pragma unroll
            for (int q = 0; q < 4; ++q) v += wap[q * WAP_STRIDE + tid];
            v_s[tid] = v;
        }
        __syncthreads();                            // (2)

        // ---- A2: flash attention over own 256-t half. Wave owns 16 t; lane owns 4 e's.
        {
            float4 v4 = *reinterpret_cast<const float4*>(&v_s[lane * 4]);
            float m = -3e38f, l = 0.f;
            float c0 = 0.f, c1 = 0.f, c2 = 0.f, c3 = 0.f;
            const float* sw = sigb + (size_t)(wv * 16) * EDIM + lane * 4;
#pragma unroll 4
            for (int i = 0; i < 16; i += 2) {
                float4 A = *reinterpret_cast<const float4*>(sw + (size_t)i * EDIM);
                float4 Bv = *reinterpret_cast<const float4*>(sw + (size_t)(i + 1) * EDIM);
                float da = A.x * v4.x + A.y * v4.y + A.z * v4.z + A.w * v4.w;
                float db = Bv.x * v4.x + Bv.y * v4.y + Bv.z * v4.z + Bv.w * v4.w;
#pragma unroll
                for (int mk = 32; mk > 0; mk >>= 1) {
                    da += __shfl_xor(da, mk, 64);
                    db += __shfl_xor(db, mk, 64);
                }
                float ea = da + embias_s[wv * 16 + i];
                float eb = db + embias_s[wv * 16 + i + 1];
                float mn = fmaxf(m, fmaxf(ea, eb));
                float sc = __expf(m - mn);
                float pa = __expf(ea - mn);
                float pb = __expf(eb - mn);
                l  = l  * sc + pa + pb;
                c0 = c0 * sc + pa * A.x + pb * Bv.x;
                c1 = c1 * sc + pa * A.y + pb * Bv.y;
                c2 = c2 * sc + pa * A.z + pb * Bv.z;
                c3 = c3 * sc + pa * A.w + pb * Bv.w;
                m = mn;
            }
            if (lane == 0) { mw_s[wv] = m; lw_s[wv] = l; }
            float4 cc; cc.x = c0; cc.y = c1; cc.z = c2; cc.w = c3;
            *reinterpret_cast<float4*>(&ctxp[wv * EDIM + lane * 4]) = cc;
        }
        __syncthreads();                            // (3)

        // ---- half-combine + publish (unnormalized ctx in frame Mme) ----
        if (tid < NWAVES) {
            float M = mw_s[0];
#pragma unroll
            for (int w = 1; w < NWAVES; ++w) M = fmaxf(M, mw_s[w]);
            ews_s[tid] = __expf(mw_s[tid] - M);
            if (tid == 0) scr2[0] = M;
        }
        __syncthreads();                            // (4)
        float cmine = 0.f;
        if (tid < EDIM) {
#pragma unroll
            for (int w = 0; w < NWAVES; ++w) cmine += ews_s[w] * ctxp[w * EDIM + tid];
            st_agent(myctx + tid, cmine);
        } else if (tid == EDIM) {
            float L = 0.f;
#pragma unroll
            for (int w = 0; w < NWAVES; ++w) L += ews_s[w] * lw_s[w];
            scr2[3] = L;
            st_agent(myctx + 256, L);
            st_agent(myctx + 257, scr2[0]);
        }
        __syncthreads();                            // (A) payload stores drained (vmcnt)
        {
            const unsigned int want = (unsigned int)(2 * s + 1);
            if (tid == 0) {
                __hip_atomic_store(myflag, want, __ATOMIC_RELAXED, __HIP_MEMORY_SCOPE_AGENT);
                while (__hip_atomic_load(pflag, __ATOMIC_RELAXED, __HIP_MEMORY_SCOPE_AGENT) < want)
                    __builtin_amdgcn_s_sleep(4);
                __atomic_signal_fence(__ATOMIC_SEQ_CST);
                scr2[1] = ld_agent(pctx + 257);     // Mp
                scr2[2] = ld_agent(pctx + 256);     // Lp
            }
        }
        __syncthreads();                            // (B)
        {
            float Mme = scr2[0], Mp = scr2[1], Lp = scr2[2], Lme = scr2[3];
            float M = fmaxf(Mme, Mp);
            float ame = __expf(Mme - M), ap = __expf(Mp - M);
            float L = Lme * ame + Lp * ap;
            if (tid < EDIM)
                inp_s[EDIM + tid] = (cmine * ame + ld_agent(pctx + tid) * ap) / L;
        }
        __syncthreads();                            // (5) inp ready

        // ---- LayerNorm over 2E=512, single pass ----
        {
            float val = (tid < 2 * EDIM) ? inp_s[tid] : 0.f;
            float s1 = val, s2 = val * val;
#pragma unroll
            for (int mk = 32; mk > 0; mk >>= 1) {
                s1 += __shfl_xor(s1, mk, 64);
                s2 += __shfl_xor(s2, mk, 64);
            }
            if (lane == 0) { scr2[wv] = s1; scr2[NWAVES + wv] = s2; }
            __syncthreads();                        // (6)
            float S1 = 0.f, S2 = 0.f;
#pragma unroll
            for (int w = 0; w < NWAVES; ++w) { S1 += scr2[w]; S2 += scr2[NWAVES + w]; }
            float mu  = S1 * (1.0f / (2 * EDIM));
            float var = S2 * (1.0f / (2 * EDIM)) - mu * mu;
            float rs  = rsqrtf(var + 1e-5f);
            if (tid < 2 * EDIM) inpn_s[tid] = (val - mu) * rs * slng[tid] + slnb[tid];
        }
        __syncthreads();                            // (7)

        // ---- GX: gx_own = wih_own @ inpn (384x512). 768 workers, 8-way k-split. ----
        if (tid < 768) {
            const int q  = tid & 7;
            const int r4 = (tid >> 3) * 4;          // 0..380
            const float* base = wihTr + (size_t)(q * 64) * GX_ROWS + r4;
            const float* xk = &inpn_s[q * 64];
            float a0 = 0.f, a1 = 0.f, a2 = 0.f, a3 = 0.f;
#pragma unroll 8
            for (int k = 0; k < 64; ++k) {
                float4 w4 = *reinterpret_cast<const float4*>(base + (size_t)k * GX_ROWS);
                float x = xk[k];
                a0 += w4.x * x; a1 += w4.y * x; a2 += w4.z * x; a3 += w4.w * x;
            }
            float4 acc; acc.x = a0; acc.y = a1; acc.z = a2; acc.w = a3;
            *reinterpret_cast<float4*>(&gxp[q * GXP_STRIDE + r4]) = acc;
        }
        __syncthreads();                            // (8)

        // ---- gates for own j-half (torch order r,z,n) ----
        if (tid < JH) {
            const int jl = tid, j = joff + jl;
            float xr = sbih[j], xz = sbih[EDIM + j], xn = sbih[2 * EDIM + j];
#pragma unroll
            for (int q = 0; q < 8; ++q) {
                xr += gxp[q * GXP_STRIDE + jl];
                xz += gxp[q * GXP_STRIDE + JH + jl];
                xn += gxp[q * GXP_STRIDE + 2 * JH + jl];
            }
            float hr = sbhh[j], hz = sbhh[EDIM + j], hn_ = sbhh[2 * EDIM + j];
#pragma unroll
            for (int q = 0; q < 4; ++q) {
                hr  += wap[q * WAP_STRIDE + 256 + jl];
                hz  += wap[q * WAP_STRIDE + 384 + jl];
                hn_ += wap[q * WAP_STRIDE + 512 + jl];
            }
            float r = 1.0f / (1.0f + __expf(-(xr + hr)));
            float z = 1.0f / (1.0f + __expf(-(xz + hz)));
            float n = tanhf(xn + r * hn_);
            float hnew = (1.0f - z) * n + z * h_s[j];
            h_s[j] = hnew;
            out[((size_t)b * SLEN + s) * EDIM + j] = hnew;
            st_agent(myh + jl, hnew);
        }
        __syncthreads();                            // (C) h payload drained
        {
            const unsigned int want = (unsigned int)(2 * s + 2);
            if (tid == 0) {
                __hip_atomic_store(myflag, want, __ATOMIC_RELAXED, __HIP_MEMORY_SCOPE_AGENT);
                while (__hip_atomic_load(pflag, __ATOMIC_RELAXED, __HIP_MEMORY_SCOPE_AGENT) < want)
                    __builtin_amdgcn_s_sleep(4);
                __atomic_signal_fence(__ATOMIC_SEQ_CST);
            }
        }
        __syncthreads();                            // (D)
        if (tid < JH) h_s[(JH - joff) + tid] = ld_agent(ph + tid);
        __syncthreads();                            // (9) full h ready
    }
}

extern "C" void kernel_launch(void* const* d_in, const int* in_sizes, int n_in,
                              void* d_out, int out_size, void* d_ws, size_t ws_size,
                              hipStream_t stream) {
    const float* signal = (const float*)d_in[0];
    const float* bases  = (const float*)d_in[1];
    const int*   mask   = (const int*)d_in[2];
    const float* Ww     = (const float*)d_in[3];
    const float* Wb     = (const float*)d_in[4];
    const float* lng    = (const float*)d_in[5];
    const float* lnb    = (const float*)d_in[6];
    const float* wih    = (const float*)d_in[7];
    const float* bih    = (const float*)d_in[8];
    const float* whh    = (const float*)d_in[9];
    const float* bhh    = (const float*)d_in[10];
    const float* hinit  = (const float*)d_in[11];
    float*       out    = (float*)d_out;

    const int B = in_sizes[0] / (TLEN * EDIM);   // 128

    // workspace: WA[2][256][640] | wihT[2][512][384] | payload[128][1024] | flags[128][64] (~3.3 MB)
    float* WA      = (float*)d_ws;
    float* wihT    = WA + 2 * 256 * WA_ROWS;
    float* payload = wihT + 2 * 512 * GX_ROWS;
    unsigned int* flags = (unsigned int*)(payload + 128 * 1024);

    hipMemsetAsync(flags, 0, 128 * 64 * sizeof(unsigned int), stream);
    pack_fused_kernel<<<dim3(8, 4, 14), 256, 0, stream>>>(Ww, whh, wih, WA, wihT);
    gru_decoder_kernel<<<dim3(2 * B), dim3(NT), 0, stream>>>(
        signal, bases, mask, WA, Wb, lng, lnb, wihT, bih, bhh, hinit, payload, flags, out, 0);
}

// Round 5
// 2085.452 us; speedup vs baseline: 1.6786x; 1.6786x over previous
//
#include <hip/hip_runtime.h>

// Problem constants
#define EDIM 256
#define SLEN 64
#define TLEN 512
#define NT 1024
#define NWAVES 16
#define JH 128            // j-half (gate rows per role)
#define WA_ROWS 640       // 256 (Ww rows) + 384 (whh own-gate rows)
#define GX_ROWS 384

// ---- fused pack prepass (verified rounds 3-4) ----
// z in [0,6):  whh role/gate slices -> WA[role][k][256 + g*128 + j] = whh[g*256+role*128+j][k]
// z in [6,12): wih role/gate slices -> wihT[role][k][g*128 + j]     = wih[g*256+role*128+j][k]
// z in [12,14): Ww for role z-12    -> WA[role][k][j]               = Ww[j][k]
__global__ __launch_bounds__(256) void pack_fused_kernel(
    const float* __restrict__ Ww, const float* __restrict__ whh,
    const float* __restrict__ wih, float* __restrict__ WA, float* __restrict__ wihT)
{
    const int z = blockIdx.z;
    const float* in; float* out; int R, C, ostride, ooff;
    if (z < 12) {
        int mat = z / 6, rem = z % 6, role = rem / 3, g = rem % 3;
        if (mat == 0) {
            in = whh + (size_t)(g * 256 + role * JH) * 256; C = 256;
            out = WA + (size_t)role * 256 * WA_ROWS; ostride = WA_ROWS; ooff = 256 + g * JH; R = JH;
        } else {
            in = wih + (size_t)(g * 256 + role * JH) * 512; C = 512;
            out = wihT + (size_t)role * 512 * GX_ROWS; ostride = GX_ROWS; ooff = g * JH; R = JH;
        }
    } else {
        int role = z - 12; in = Ww; C = 256;
        out = WA + (size_t)role * 256 * WA_ROWS; ostride = WA_ROWS; ooff = 0; R = 256;
    }
    const int r0 = blockIdx.y * 64, c0 = blockIdx.x * 64;
    if (r0 >= R || c0 >= C) return;
    __shared__ float tile[64][65];
    for (int i = threadIdx.x; i < 64 * 64; i += 256) {
        int r = i >> 6, c = i & 63;
        tile[r][c] = in[(size_t)(r0 + r) * C + (c0 + c)];
    }
    __syncthreads();
    for (int i = threadIdx.x; i < 64 * 64; i += 256) {
        int c = i >> 6, r = i & 63;
        out[(size_t)(c0 + c) * ostride + ooff + (r0 + r)] = tile[r][c];
    }
}

__global__ __launch_bounds__(NT) void gru_decoder_kernel(
    const float* __restrict__ signal,   // [B,T,E]
    const float* __restrict__ bases,    // [B,S,E]
    const int* __restrict__ mask,       // [B,T]
    const float* __restrict__ WA,       // [2][256k][640r]
    const float* __restrict__ Wb,
    const float* __restrict__ lng, const float* __restrict__ lnb,
    const float* __restrict__ wihT,     // [2][512k][384r]
    const float* __restrict__ bih, const float* __restrict__ bhh,
    const float* __restrict__ hinit,
    unsigned long long* __restrict__ payload,  // [B][2 parity][2 role][128] tagged words
    float* __restrict__ out, int nb, int never)
{
    const int bid  = blockIdx.x;
    const int pair = bid % nb;          // batch index (roles p and p+nb share an XCD under round-robin)
    const int role = bid / nb;
    const int b    = pair;
    const int joff = role * JH;
    const int tid  = threadIdx.x;
    const int lane = tid & 63;
    const int wv   = tid >> 6;

    __shared__ float h_s[EDIM], v_s[EDIM];
    __shared__ float wap[4 * WA_ROWS];        // A1 partials: rows 0..255 v, 256..639 gh_own (live to gates)
    __shared__ float ctxp[NWAVES * EDIM];
    __shared__ float mw_s[NWAVES], lw_s[NWAVES], ews_s[NWAVES];
    __shared__ float inp_s[2 * EDIM], inpn_s[2 * EDIM];
    __shared__ float gxp[8 * GX_ROWS];
    __shared__ float embias_s[TLEN];
    __shared__ float scr2[2 * NWAVES];
    __shared__ float sWb[EDIM], sbih[768], sbhh[768], slng[512], slnb[512];
    __shared__ float pad_lds[8 * 1024];       // occupancy limiter -> 1 block/CU (co-residency)
    if (never) { pad_lds[tid] = (float)never; v_s[0] = pad_lds[(tid + 1) & 8191]; }

    const float* WAr   = WA   + (size_t)role * 256 * WA_ROWS;
    const float* wihTr = wihT + (size_t)role * 512 * GX_ROWS;
    const float* sigb  = signal + (size_t)b * TLEN * EDIM;
    const int*   maskb = mask + (size_t)b * TLEN;

    unsigned long long* pbuf = payload + (size_t)pair * 512;

    if (tid < 256) { h_s[tid] = hinit[tid]; sWb[tid] = Wb[tid]; }
    if (tid < 512) { embias_s[tid] = maskb[tid] ? -1e30f : 0.0f; slng[tid] = lng[tid]; slnb[tid] = lnb[tid]; }
    if (tid < 768) { sbih[tid] = bih[tid]; sbhh[tid] = bhh[tid]; }
    __syncthreads();

    for (int s = 0; s < SLEN; ++s) {
        // ---- A1: [v; gh_own] = WA_role @ h. 4-way k-split, q WAVE-UNIFORM (tid>>8).
        //      Within q-group: workers w<160 own 4 rows (float4, contiguous 1KB/wave).
        //      Idle workers (w>=160) prefetch x into inp_s[0..255].
        {
            const int q = tid >> 8;             // 0..3 wave-uniform
            const int w = tid & 255;
            if (w < 160) {
                const int r4 = w * 4;           // 0..636
                const float* base = WAr + (size_t)(q * 64) * WA_ROWS + r4;
                const float* xk = &h_s[q * 64];
                float a0 = 0.f, a1 = 0.f, a2 = 0.f, a3 = 0.f;
#pragma unroll 8
                for (int k = 0; k < 64; ++k) {
                    float4 w4 = *reinterpret_cast<const float4*>(base + (size_t)k * WA_ROWS);
                    float x = xk[k];
                    a0 += w4.x * x; a1 += w4.y * x; a2 += w4.z * x; a3 += w4.w * x;
                }
                float4 acc; acc.x = a0; acc.y = a1; acc.z = a2; acc.w = a3;
                *reinterpret_cast<float4*>(&wap[q * WA_ROWS + r4]) = acc;
            } else {
                const int li = q * 96 + (w - 160);   // 0..383
                if (li < 256) inp_s[li] = bases[((size_t)b * SLEN + s) * EDIM + li];
            }
        }
        __syncthreads();                        // (1)
        if (tid < EDIM) {
            float v = sWb[tid];
#pragma unroll
            for (int q = 0; q < 4; ++q) v += wap[q * WA_ROWS + tid];
            v_s[tid] = v;
        }
        __syncthreads();                        // (2)

        // ---- Attention over full T=512 (duplicated across pair; round-1 structure).
        //      Wave owns 32 consecutive t; lane owns e-slice [lane*4, lane*4+4).
        {
            float4 v4 = *reinterpret_cast<const float4*>(&v_s[lane * 4]);
            float m = -3e38f, l = 0.f;
            float c0 = 0.f, c1 = 0.f, c2 = 0.f, c3 = 0.f;
            const int t0 = wv * 32;
#pragma unroll 4
            for (int i = 0; i < 32; i += 2) {
                const int ta = t0 + i, tb = ta + 1;
                float4 A  = *reinterpret_cast<const float4*>(sigb + (size_t)ta * EDIM + lane * 4);
                float4 Bv = *reinterpret_cast<const float4*>(sigb + (size_t)tb * EDIM + lane * 4);
                float da = A.x * v4.x + A.y * v4.y + A.z * v4.z + A.w * v4.w;
                float db = Bv.x * v4.x + Bv.y * v4.y + Bv.z * v4.z + Bv.w * v4.w;
#pragma unroll
                for (int mk = 32; mk > 0; mk >>= 1) {
                    da += __shfl_xor(da, mk, 64);
                    db += __shfl_xor(db, mk, 64);
                }
                float ea = da + embias_s[ta];
                float eb = db + embias_s[tb];
                float mn = fmaxf(m, fmaxf(ea, eb));
                float sc = __expf(m - mn);
                float pa = __expf(ea - mn);
                float pb = __expf(eb - mn);
                l  = l  * sc + pa + pb;
                c0 = c0 * sc + pa * A.x + pb * Bv.x;
                c1 = c1 * sc + pa * A.y + pb * Bv.y;
                c2 = c2 * sc + pa * A.z + pb * Bv.z;
                c3 = c3 * sc + pa * A.w + pb * Bv.w;
                m = mn;
            }
            if (lane == 0) { mw_s[wv] = m; lw_s[wv] = l; }
            float4 cc; cc.x = c0; cc.y = c1; cc.z = c2; cc.w = c3;
            *reinterpret_cast<float4*>(&ctxp[wv * EDIM + lane * 4]) = cc;
        }
        __syncthreads();                        // (3)

        if (tid < NWAVES) {
            float M = mw_s[0];
#pragma unroll
            for (int w = 1; w < NWAVES; ++w) M = fmaxf(M, mw_s[w]);
            ews_s[tid] = __expf(mw_s[tid] - M);
        }
        __syncthreads();                        // (4)

        if (tid < EDIM) {
            float L = 0.f, c = 0.f;
#pragma unroll
            for (int w = 0; w < NWAVES; ++w) {
                float ew = ews_s[w];
                L += lw_s[w] * ew;
                c += ctxp[w * EDIM + tid] * ew;
            }
            inp_s[EDIM + tid] = c / L;
        }
        __syncthreads();                        // (5) inp ready (x half loaded in A1)

        // ---- LayerNorm over 2E=512, single pass ----
        {
            float val = (tid < 2 * EDIM) ? inp_s[tid] : 0.f;
            float s1 = val, s2 = val * val;
#pragma unroll
            for (int mk = 32; mk > 0; mk >>= 1) {
                s1 += __shfl_xor(s1, mk, 64);
                s2 += __shfl_xor(s2, mk, 64);
            }
            if (lane == 0) { scr2[wv] = s1; scr2[NWAVES + wv] = s2; }
            __syncthreads();                    // (6)
            float S1 = 0.f, S2 = 0.f;
#pragma unroll
            for (int w = 0; w < NWAVES; ++w) { S1 += scr2[w]; S2 += scr2[NWAVES + w]; }
            float mu  = S1 * (1.0f / (2 * EDIM));
            float var = S2 * (1.0f / (2 * EDIM)) - mu * mu;
            float rs  = rsqrtf(var + 1e-5f);
            if (tid < 2 * EDIM) inpn_s[tid] = (val - mu) * rs * slng[tid] + slnb[tid];
        }
        __syncthreads();                        // (7)

        // ---- GX: gx_own = wih_own @ inpn (384x512). 8-way k-split, q WAVE-UNIFORM (tid>>7).
        {
            const int q = tid >> 7;             // 0..7 wave-uniform
            const int w = tid & 127;
            if (w < 96) {
                const int r4 = w * 4;           // 0..380
                const float* base = wihTr + (size_t)(q * 64) * GX_ROWS + r4;
                const float* xk = &inpn_s[q * 64];
                float a0 = 0.f, a1 = 0.f, a2 = 0.f, a3 = 0.f;
#pragma unroll 8
                for (int k = 0; k < 64; ++k) {
                    float4 w4 = *reinterpret_cast<const float4*>(base + (size_t)k * GX_ROWS);
                    float x = xk[k];
                    a0 += w4.x * x; a1 += w4.y * x; a2 += w4.z * x; a3 += w4.w * x;
                }
                float4 acc; acc.x = a0; acc.y = a1; acc.z = a2; acc.w = a3;
                *reinterpret_cast<float4*>(&gxp[q * GX_ROWS + r4]) = acc;
            }
        }
        __syncthreads();                        // (8)

        // ---- gates for own j-half (torch order r,z,n) + tagged-word h exchange ----
        // word = (s+1)<<32 | float_bits: tag+data arrive atomically -> no ordering assumptions.
        {
            unsigned long long* myslot = pbuf + (s & 1) * 256 + role * JH;
            unsigned long long* pslot  = pbuf + (s & 1) * 256 + (1 - role) * JH;
            if (tid < JH) {
                const int jl = tid, j = joff + jl;
                float xr = sbih[j], xz = sbih[EDIM + j], xn = sbih[2 * EDIM + j];
#pragma unroll
                for (int q = 0; q < 8; ++q) {
                    xr += gxp[q * GX_ROWS + jl];
                    xz += gxp[q * GX_ROWS + JH + jl];
                    xn += gxp[q * GX_ROWS + 2 * JH + jl];
                }
                float hr = sbhh[j], hz = sbhh[EDIM + j], hn_ = sbhh[2 * EDIM + j];
#pragma unroll
                for (int q = 0; q < 4; ++q) {
                    hr  += wap[q * WA_ROWS + 256 + jl];
                    hz  += wap[q * WA_ROWS + 384 + jl];
                    hn_ += wap[q * WA_ROWS + 512 + jl];
                }
                float r = 1.0f / (1.0f + __expf(-(xr + hr)));
                float z = 1.0f / (1.0f + __expf(-(xz + hz)));
                float n = tanhf(xn + r * hn_);
                float hnew = (1.0f - z) * n + z * h_s[j];
                h_s[j] = hnew;
                out[((size_t)b * SLEN + s) * EDIM + j] = hnew;

                const unsigned int want = (unsigned int)(s + 1);
                unsigned long long wrd = ((unsigned long long)want << 32)
                                       | (unsigned long long)__float_as_uint(hnew);
                __hip_atomic_store(myslot + jl, wrd, __ATOMIC_RELAXED, __HIP_MEMORY_SCOPE_AGENT);
                unsigned long long pw;
                for (;;) {
                    pw = __hip_atomic_load(pslot + jl, __ATOMIC_RELAXED, __HIP_MEMORY_SCOPE_AGENT);
                    if ((unsigned int)(pw >> 32) >= want) break;
                    __builtin_amdgcn_s_sleep(1);
                }
                h_s[(JH - joff) + jl] = __uint_as_float((unsigned int)pw);
            }
        }
        __syncthreads();                        // (9) full h ready
    }
}

extern "C" void kernel_launch(void* const* d_in, const int* in_sizes, int n_in,
                              void* d_out, int out_size, void* d_ws, size_t ws_size,
                              hipStream_t stream) {
    const float* signal = (const float*)d_in[0];
    const float* bases  = (const float*)d_in[1];
    const int*   mask   = (const int*)d_in[2];
    const float* Ww     = (const float*)d_in[3];
    const float* Wb     = (const float*)d_in[4];
    const float* lng    = (const float*)d_in[5];
    const float* lnb    = (const float*)d_in[6];
    const float* wih    = (const float*)d_in[7];
    const float* bih    = (const float*)d_in[8];
    const float* whh    = (const float*)d_in[9];
    const float* bhh    = (const float*)d_in[10];
    const float* hinit  = (const float*)d_in[11];
    float*       out    = (float*)d_out;

    const int B = in_sizes[0] / (TLEN * EDIM);   // 128

    // workspace: WA[2][256][640] | wihT[2][512][384] | payload u64[B][512]  (~3.4 MB)
    float* WA   = (float*)d_ws;
    float* wihT = WA + 2 * 256 * WA_ROWS;
    unsigned long long* payload = (unsigned long long*)(wihT + 2 * 512 * GX_ROWS);

    hipMemsetAsync(payload, 0, (size_t)B * 512 * sizeof(unsigned long long), stream);
    pack_fused_kernel<<<dim3(8, 4, 14), 256, 0, stream>>>(Ww, whh, wih, WA, wihT);
    gru_decoder_kernel<<<dim3(2 * B), dim3(NT), 0, stream>>>(
        signal, bases, mask, WA, Wb, lng, lnb, wihT, bih, bhh, hinit, payload, out, B, 0);
}